// Round 7
// baseline (209.806 us; speedup 1.0000x reference)
//
#include <hip/hip_runtime.h>
#include <hip/hip_fp16.h>

#define GRAVITY_F 9.81f
#define EPT 4  // elements per thread
#define VPT 4  // vertices per thread

typedef int   v4i __attribute__((ext_vector_type(4)));
typedef float v4f __attribute__((ext_vector_type(4), aligned(4)));   // 4-B aligned dwordx4
typedef float v4fa __attribute__((ext_vector_type(4), aligned(16)));

union PackedPos { uint2 u; __half h[4]; };

__device__ __forceinline__ float blockReduceSum(float val) {
    #pragma unroll
    for (int off = 32; off > 0; off >>= 1)
        val += __shfl_down(val, off, 64);
    __shared__ float smem[16];
    const int lane = threadIdx.x & 63;
    const int wave = threadIdx.x >> 6;
    if (lane == 0) smem[wave] = val;
    __syncthreads();
    const int nwaves = (blockDim.x + 63) >> 6;
    val = 0.0f;
    if (wave == 0) {
        if (lane < nwaves) val = smem[lane];
        #pragma unroll
        for (int off = 8; off > 0; off >>= 1)
            val += __shfl_down(val, off, 64);
    }
    return val;  // valid on thread 0 only
}

// Pack pos_next (fp32 x,y,z) -> half4 (8 B/vertex, 4 MB total) so the gather
// target fits a 4 MiB per-XCD L2. Cached write: we WANT it resident.
__global__ void pack_kernel(const float* __restrict__ pn,
                            uint2* __restrict__ out, int V) {
    const int v = blockIdx.x * blockDim.x + threadIdx.x;
    if (v >= V) return;
    PackedPos p;
    p.h[0] = __float2half(__builtin_nontemporal_load(pn + 3 * v + 0));
    p.h[1] = __float2half(__builtin_nontemporal_load(pn + 3 * v + 1));
    p.h[2] = __float2half(__builtin_nontemporal_load(pn + 3 * v + 2));
    p.h[3] = __half(0.0f);
    out[v] = p.u;
}

// Blocks [0, Eblocks): element terms, EPT elems/thread.
// Blocks [Eblocks, ...): vertex terms, VPT vertices/thread (exact fp32).
__global__ void __launch_bounds__(256, 4)
fused_kernel(const float* __restrict__ pn,
             const float* __restrict__ pc,
             const float* __restrict__ pp,
             const float* __restrict__ mass,
             const int*   __restrict__ elems,
             const float* __restrict__ vols,
             const float* __restrict__ rinv,
             const float* __restrict__ lam_p,
             const float* __restrict__ mu_p,
             const uint2* __restrict__ packed4,
             float* __restrict__ partials,
             int V, int E, int Eblocks,
             float sI, float sG, float sS) {
    float local = 0.0f;

    if ((int)blockIdx.x < Eblocks) {
        const float lam = lam_p[0];
        const float mu  = mu_p[0];
        const int base = blockIdx.x * (EPT * 256) + threadIdx.x;

        int  ec[EPT];
        float sc[EPT];
        #pragma unroll
        for (int i = 0; i < EPT; ++i) {
            const int e = base + i * 256;
            ec[i] = e < E ? e : (E - 1);
            sc[i] = e < E ? sS : 0.0f;
        }
        v4i  idx[EPT];
        float vol[EPT];
        #pragma unroll
        for (int i = 0; i < EPT; ++i) {
            idx[i] = __builtin_nontemporal_load(((const v4i*)elems) + ec[i]);
            vol[i] = __builtin_nontemporal_load(vols + ec[i]);
        }

        // Vertex gathers from the L2-resident packed copy (8 B each)
        uint2 g[EPT][4];
        #pragma unroll
        for (int i = 0; i < EPT; ++i) {
            g[i][0] = packed4[idx[i].x];
            g[i][1] = packed4[idx[i].y];
            g[i][2] = packed4[idx[i].z];
            g[i][3] = packed4[idx[i].w];
        }

        // rest_inv: 9 floats/elem as dwordx4 + dwordx4 + dword (nontemporal)
        float R[EPT][9];
        #pragma unroll
        for (int i = 0; i < EPT; ++i) {
            const float* Rp = rinv + 9 * (size_t)ec[i];
            const v4f a = __builtin_nontemporal_load((const v4f*)(Rp + 0));
            const v4f b = __builtin_nontemporal_load((const v4f*)(Rp + 4));
            const float c = __builtin_nontemporal_load(Rp + 8);
            R[i][0] = a.x; R[i][1] = a.y; R[i][2] = a.z; R[i][3] = a.w;
            R[i][4] = b.x; R[i][5] = b.y; R[i][6] = b.z; R[i][7] = b.w;
            R[i][8] = c;
        }

        #pragma unroll
        for (int i = 0; i < EPT; ++i) {
            float x[4][3];
            #pragma unroll
            for (int j = 0; j < 4; ++j) {
                PackedPos p; p.u = g[i][j];
                x[j][0] = __half2float(p.h[0]);
                x[j][1] = __half2float(p.h[1]);
                x[j][2] = __half2float(p.h[2]);
            }
            float d[3][3];
            #pragma unroll
            for (int r = 0; r < 3; ++r) {
                d[r][0] = x[1][r] - x[0][r];
                d[r][1] = x[2][r] - x[0][r];
                d[r][2] = x[3][r] - x[0][r];
            }
            float F[3][3];
            #pragma unroll
            for (int r = 0; r < 3; ++r)
                #pragma unroll
                for (int k = 0; k < 3; ++k)
                    F[r][k] = d[r][0] * R[i][0 * 3 + k]
                            + d[r][1] * R[i][1 * 3 + k]
                            + d[r][2] * R[i][2 * 3 + k];
            const float det = F[0][0] * (F[1][1] * F[2][2] - F[1][2] * F[2][1])
                            - F[0][1] * (F[1][0] * F[2][2] - F[1][2] * F[2][0])
                            + F[0][2] * (F[1][0] * F[2][1] - F[1][1] * F[2][0]);
            const float ld = logf(fmaxf(det, 1e-8f));
            float tr = 0.0f;
            #pragma unroll
            for (int r = 0; r < 3; ++r)
                #pragma unroll
                for (int k = 0; k < 3; ++k)
                    tr += F[r][k] * F[r][k];
            const float psi = 0.5f * lam * ld * ld - mu * ld + 0.5f * mu * (tr - 3.0f);
            local += sc[i] * (psi * vol[i]);
        }
    } else {
        const int t = (blockIdx.x - Eblocks) * blockDim.x + threadIdx.x;
        const int v0 = t * VPT;
        if (v0 + VPT <= V) {
            // 16-B aligned vector loads: 12 floats = 3 dwordx4 per array
            v4fa n[3], c[3], q[3];
            #pragma unroll
            for (int k = 0; k < 3; ++k) {
                n[k] = __builtin_nontemporal_load(((const v4fa*)pn) + 3 * t + k);
                c[k] = __builtin_nontemporal_load(((const v4fa*)pc) + 3 * t + k);
                q[k] = __builtin_nontemporal_load(((const v4fa*)pp) + 3 * t + k);
            }
            const v4fa m4 = __builtin_nontemporal_load(((const v4fa*)mass) + t);
            const float* nf = (const float*)n;
            const float* cf = (const float*)c;
            const float* qf = (const float*)q;
            const float* mf = (const float*)&m4;
            #pragma unroll
            for (int j = 0; j < VPT; ++j) {
                const float m  = mf[j];
                const float y  = cf[3 * j + 1];
                const float a0 = nf[3 * j + 0] + qf[3 * j + 0] - 2.0f * cf[3 * j + 0];
                const float a1 = nf[3 * j + 1] + qf[3 * j + 1] - 2.0f * y;
                const float a2 = nf[3 * j + 2] + qf[3 * j + 2] - 2.0f * cf[3 * j + 2];
                local += sI * (m * (a0 * a0 + a1 * a1 + a2 * a2)) + sG * (m * y);
            }
        } else {
            for (int v = v0; v < V; ++v) {
                const float m  = mass[v];
                const float y  = pc[3 * v + 1];
                const float a0 = pn[3 * v + 0] + pp[3 * v + 0] - 2.0f * pc[3 * v + 0];
                const float a1 = pn[3 * v + 1] + pp[3 * v + 1] - 2.0f * y;
                const float a2 = pn[3 * v + 2] + pp[3 * v + 2] - 2.0f * pc[3 * v + 2];
                local += sI * (m * (a0 * a0 + a1 * a1 + a2 * a2)) + sG * (m * y);
            }
        }
    }

    const float tot = blockReduceSum(local);
    if (threadIdx.x == 0) partials[blockIdx.x] = tot;
}

__global__ void reduce_kernel(const float* __restrict__ partials, int n,
                              float* __restrict__ out) {
    double s = 0.0;
    for (int i = threadIdx.x; i < n; i += blockDim.x)
        s += (double)partials[i];
    __shared__ double sm[256];
    sm[threadIdx.x] = s;
    __syncthreads();
    #pragma unroll
    for (int off = 128; off > 0; off >>= 1) {
        if (threadIdx.x < off) sm[threadIdx.x] += sm[threadIdx.x + off];
        __syncthreads();
    }
    if (threadIdx.x == 0) out[0] = (float)sm[0];
}

extern "C" void kernel_launch(void* const* d_in, const int* in_sizes, int n_in,
                              void* d_out, int out_size, void* d_ws, size_t ws_size,
                              hipStream_t stream) {
    const float* pos_next = (const float*)d_in[0];
    const float* pos_curr = (const float*)d_in[1];
    const float* pos_prev = (const float*)d_in[2];
    const float* mass     = (const float*)d_in[3];
    const int*   elements = (const int*)d_in[4];
    const float* rest_vol = (const float*)d_in[5];
    const float* rest_inv = (const float*)d_in[6];
    const float* lam_p    = (const float*)d_in[7];
    const float* mu_p     = (const float*)d_in[8];
    float* out = (float*)d_out;

    const int V = in_sizes[3];  // mass has V elements
    const int E = in_sizes[5];  // rest_volumes has E elements

    const float sI = 0.5f / (3.0f * (float)V);       // W_INERTIA * 0.5 / (3V)
    const float sG = -0.01f * GRAVITY_F / (float)V;  // W_GRAVITY * (-g) / V
    const float sS = 1.0f / (float)E;                // W_STRAIN / E

    const int block = 256;
    const int Eblocks = (E + EPT * block - 1) / (EPT * block);
    const int Vblocks = (V + VPT * block - 1) / (VPT * block);
    const int grid = Eblocks + Vblocks;

    float* partials = (float*)d_ws;  // grid floats; every slot overwritten
    const size_t part_bytes = ((size_t)grid * sizeof(float) + 255) & ~(size_t)255;

    uint2* packed4 = (uint2*)((char*)d_ws + part_bytes);
    pack_kernel<<<(V + block - 1) / block, block, 0, stream>>>(pos_next, packed4, V);
    fused_kernel<<<grid, block, 0, stream>>>(pos_next, pos_curr, pos_prev,
                                             mass, elements, rest_vol,
                                             rest_inv, lam_p, mu_p,
                                             packed4, partials,
                                             V, E, Eblocks, sI, sG, sS);
    reduce_kernel<<<1, 256, 0, stream>>>(partials, grid, out);
}

// Round 8
// 208.518 us; speedup vs baseline: 1.0062x; 1.0062x over previous
//
#include <hip/hip_runtime.h>
#include <hip/hip_fp16.h>

#define GRAVITY_F 9.81f
#define VPT 4  // vertices per thread (inertia part)

typedef int   v4i  __attribute__((ext_vector_type(4)));
typedef float v4f  __attribute__((ext_vector_type(4), aligned(4)));   // 4-B aligned dwordx4
typedef float v4fa __attribute__((ext_vector_type(4), aligned(16)));

union PackedPos { uint2 u; __half h[4]; };

__device__ __forceinline__ float blockReduceSum(float val) {
    #pragma unroll
    for (int off = 32; off > 0; off >>= 1)
        val += __shfl_down(val, off, 64);
    __shared__ float smem[16];
    const int lane = threadIdx.x & 63;
    const int wave = threadIdx.x >> 6;
    if (lane == 0) smem[wave] = val;
    __syncthreads();
    const int nwaves = (blockDim.x + 63) >> 6;
    val = 0.0f;
    if (wave == 0) {
        if (lane < nwaves) val = smem[lane];
        #pragma unroll
        for (int off = 8; off > 0; off >>= 1)
            val += __shfl_down(val, off, 64);
    }
    return val;  // valid on thread 0 only
}

// Pack pos_next (fp32 x,y,z) -> half4 (8 B/vertex, 4 MB total) so the gather
// target fits a 4 MiB per-XCD L2. Cached write: we WANT it resident.
__global__ void pack_kernel(const float* __restrict__ pn,
                            uint2* __restrict__ out, int V) {
    const int v = blockIdx.x * blockDim.x + threadIdx.x;
    if (v >= V) return;
    PackedPos p;
    p.h[0] = __float2half(__builtin_nontemporal_load(pn + 3 * v + 0));
    p.h[1] = __float2half(__builtin_nontemporal_load(pn + 3 * v + 1));
    p.h[2] = __float2half(__builtin_nontemporal_load(pn + 3 * v + 2));
    p.h[3] = __half(0.0f);
    out[v] = p.u;
}

// Blocks [0, Eblocks): element terms, 1 elem/thread (max wave count — the
// sustained memory request rate scales with resident waves, see R4-R7).
// Blocks [Eblocks, ...): vertex terms, VPT vertices/thread (exact fp32).
__global__ void
fused_kernel(const float* __restrict__ pn,
             const float* __restrict__ pc,
             const float* __restrict__ pp,
             const float* __restrict__ mass,
             const int*   __restrict__ elems,
             const float* __restrict__ vols,
             const float* __restrict__ rinv,
             const float* __restrict__ lam_p,
             const float* __restrict__ mu_p,
             const uint2* __restrict__ packed4,
             float* __restrict__ partials,
             int V, int E, int Eblocks,
             float sI, float sG, float sS) {
    float local = 0.0f;

    if ((int)blockIdx.x < Eblocks) {
        const float lam = lam_p[0];
        const float mu  = mu_p[0];
        const int e = blockIdx.x * blockDim.x + threadIdx.x;
        const int  ec = e < E ? e : (E - 1);
        const float sc = e < E ? sS : 0.0f;

        const v4i idx  = __builtin_nontemporal_load(((const v4i*)elems) + ec);
        const float vol = __builtin_nontemporal_load(vols + ec);

        // Vertex gathers from the L2-resident packed copy (8 B each)
        const uint2 g0 = packed4[idx.x];
        const uint2 g1 = packed4[idx.y];
        const uint2 g2 = packed4[idx.z];
        const uint2 g3 = packed4[idx.w];

        // rest_inv: 9 floats as dwordx4 + dwordx4 + dword (nontemporal)
        const float* Rp = rinv + 9 * (size_t)ec;
        const v4f  ra = __builtin_nontemporal_load((const v4f*)(Rp + 0));
        const v4f  rb = __builtin_nontemporal_load((const v4f*)(Rp + 4));
        const float rc = __builtin_nontemporal_load(Rp + 8);
        float R[9] = {ra.x, ra.y, ra.z, ra.w, rb.x, rb.y, rb.z, rb.w, rc};

        float x[4][3];
        {
            PackedPos p0; p0.u = g0;
            PackedPos p1; p1.u = g1;
            PackedPos p2; p2.u = g2;
            PackedPos p3; p3.u = g3;
            #pragma unroll
            for (int r = 0; r < 3; ++r) {
                x[0][r] = __half2float(p0.h[r]);
                x[1][r] = __half2float(p1.h[r]);
                x[2][r] = __half2float(p2.h[r]);
                x[3][r] = __half2float(p3.h[r]);
            }
        }

        float d[3][3];
        #pragma unroll
        for (int r = 0; r < 3; ++r) {
            d[r][0] = x[1][r] - x[0][r];
            d[r][1] = x[2][r] - x[0][r];
            d[r][2] = x[3][r] - x[0][r];
        }
        float F[3][3];
        #pragma unroll
        for (int r = 0; r < 3; ++r)
            #pragma unroll
            for (int k = 0; k < 3; ++k)
                F[r][k] = d[r][0] * R[0 * 3 + k]
                        + d[r][1] * R[1 * 3 + k]
                        + d[r][2] * R[2 * 3 + k];
        const float det = F[0][0] * (F[1][1] * F[2][2] - F[1][2] * F[2][1])
                        - F[0][1] * (F[1][0] * F[2][2] - F[1][2] * F[2][0])
                        + F[0][2] * (F[1][0] * F[2][1] - F[1][1] * F[2][0]);
        const float ld = logf(fmaxf(det, 1e-8f));
        float tr = 0.0f;
        #pragma unroll
        for (int r = 0; r < 3; ++r)
            #pragma unroll
            for (int k = 0; k < 3; ++k)
                tr += F[r][k] * F[r][k];
        const float psi = 0.5f * lam * ld * ld - mu * ld + 0.5f * mu * (tr - 3.0f);
        local = sc * (psi * vol);
    } else {
        const int t = (blockIdx.x - Eblocks) * blockDim.x + threadIdx.x;
        const int v0 = t * VPT;
        if (v0 + VPT <= V) {
            // 16-B aligned vector loads: 12 floats = 3 dwordx4 per array
            v4fa n[3], c[3], q[3];
            #pragma unroll
            for (int k = 0; k < 3; ++k) {
                n[k] = __builtin_nontemporal_load(((const v4fa*)pn) + 3 * t + k);
                c[k] = __builtin_nontemporal_load(((const v4fa*)pc) + 3 * t + k);
                q[k] = __builtin_nontemporal_load(((const v4fa*)pp) + 3 * t + k);
            }
            const v4fa m4 = __builtin_nontemporal_load(((const v4fa*)mass) + t);
            const float* nf = (const float*)n;
            const float* cf = (const float*)c;
            const float* qf = (const float*)q;
            const float* mf = (const float*)&m4;
            #pragma unroll
            for (int j = 0; j < VPT; ++j) {
                const float m  = mf[j];
                const float y  = cf[3 * j + 1];
                const float a0 = nf[3 * j + 0] + qf[3 * j + 0] - 2.0f * cf[3 * j + 0];
                const float a1 = nf[3 * j + 1] + qf[3 * j + 1] - 2.0f * y;
                const float a2 = nf[3 * j + 2] + qf[3 * j + 2] - 2.0f * cf[3 * j + 2];
                local += sI * (m * (a0 * a0 + a1 * a1 + a2 * a2)) + sG * (m * y);
            }
        } else {
            for (int v = v0; v < V; ++v) {
                const float m  = mass[v];
                const float y  = pc[3 * v + 1];
                const float a0 = pn[3 * v + 0] + pp[3 * v + 0] - 2.0f * pc[3 * v + 0];
                const float a1 = pn[3 * v + 1] + pp[3 * v + 1] - 2.0f * y;
                const float a2 = pn[3 * v + 2] + pp[3 * v + 2] - 2.0f * pc[3 * v + 2];
                local += sI * (m * (a0 * a0 + a1 * a1 + a2 * a2)) + sG * (m * y);
            }
        }
    }

    const float tot = blockReduceSum(local);
    if (threadIdx.x == 0) partials[blockIdx.x] = tot;
}

__global__ void reduce_kernel(const float* __restrict__ partials, int n,
                              float* __restrict__ out) {
    double s = 0.0;
    for (int i = threadIdx.x; i < n; i += blockDim.x)
        s += (double)partials[i];
    __shared__ double sm[256];
    sm[threadIdx.x] = s;
    __syncthreads();
    #pragma unroll
    for (int off = 128; off > 0; off >>= 1) {
        if (threadIdx.x < off) sm[threadIdx.x] += sm[threadIdx.x + off];
        __syncthreads();
    }
    if (threadIdx.x == 0) out[0] = (float)sm[0];
}

extern "C" void kernel_launch(void* const* d_in, const int* in_sizes, int n_in,
                              void* d_out, int out_size, void* d_ws, size_t ws_size,
                              hipStream_t stream) {
    const float* pos_next = (const float*)d_in[0];
    const float* pos_curr = (const float*)d_in[1];
    const float* pos_prev = (const float*)d_in[2];
    const float* mass     = (const float*)d_in[3];
    const int*   elements = (const int*)d_in[4];
    const float* rest_vol = (const float*)d_in[5];
    const float* rest_inv = (const float*)d_in[6];
    const float* lam_p    = (const float*)d_in[7];
    const float* mu_p     = (const float*)d_in[8];
    float* out = (float*)d_out;

    const int V = in_sizes[3];  // mass has V elements
    const int E = in_sizes[5];  // rest_volumes has E elements

    const float sI = 0.5f / (3.0f * (float)V);       // W_INERTIA * 0.5 / (3V)
    const float sG = -0.01f * GRAVITY_F / (float)V;  // W_GRAVITY * (-g) / V
    const float sS = 1.0f / (float)E;                // W_STRAIN / E

    const int block = 256;
    const int Eblocks = (E + block - 1) / block;
    const int Vblocks = (V + VPT * block - 1) / (VPT * block);
    const int grid = Eblocks + Vblocks;

    float* partials = (float*)d_ws;  // grid floats; every slot overwritten
    const size_t part_bytes = ((size_t)grid * sizeof(float) + 255) & ~(size_t)255;

    uint2* packed4 = (uint2*)((char*)d_ws + part_bytes);
    pack_kernel<<<(V + block - 1) / block, block, 0, stream>>>(pos_next, packed4, V);
    fused_kernel<<<grid, block, 0, stream>>>(pos_next, pos_curr, pos_prev,
                                             mass, elements, rest_vol,
                                             rest_inv, lam_p, mu_p,
                                             packed4, partials,
                                             V, E, Eblocks, sI, sG, sS);
    reduce_kernel<<<1, 256, 0, stream>>>(partials, grid, out);
}